// Round 1
// baseline (1235.142 us; speedup 1.0000x reference)
//
#include <hip/hip_runtime.h>

// ---------------------------------------------------------------------------
// DeformableTransformer encoder layer, MI355X (gfx950).
// Pipeline:
//   prep_weights: f32 weights -> bf16, transposed to N x K ("Bt" layout)
//   prep_act:     src_bf = bf16(src), q_bf = bf16(src+pos), M padded to 52544
//   G1: value   = src_bf @ Wv^T + bv                       (bf16 out)
//   G2: offattn = q_bf @ [Woff|Wattn|0]^T + [boff|battn|0] (bf16 out, N=320)
//   softmax12:  in-place softmax over 12 attn logits per (token, head)
//   deform_sample: bilinear MS-deform-attn core -> attn_out (bf16)
//   G3: xpre = src + attn_out @ Wout^T + bout              (bf16 out)
//   LN1 -> x_bf
//   G4: h = relu(x_bf @ Wff1^T + bff1)                     (bf16 out, N=1024)
//   G5: y = x_bf + h @ Wff2^T + bff2                       (bf16 out)
//   LN2 -> d_out (f32)
// GEMM: 64x64 tile, MFMA 16x16x32 bf16 (m92-class), LDS pad stride 40.
// ---------------------------------------------------------------------------

#define BLTOK 52500   // B*L tokens
#define MP    52544   // BLTOK padded to multiple of 64
#define LSP   13125   // L (spatial length per batch)

using short8 = __attribute__((ext_vector_type(8))) short;
using f32x4  = __attribute__((ext_vector_type(4))) float;

__device__ __forceinline__ ushort f2b(float f) {
  union { float f; unsigned u; } x; x.f = f;
  unsigned r = (x.u + 0x7fffu + ((x.u >> 16) & 1u)) >> 16;
  return (ushort)r;
}
__device__ __forceinline__ float b2f(ushort h) {
  union { unsigned u; float f; } x; x.u = ((unsigned)h) << 16;
  return x.f;
}

// ---------------- weight prep: transpose to N x K, convert bf16 -------------
// regions: Wv_t(256x256) Wcat_t(320x256) Wout_t(256x256) Wff1_t(1024x256)
//          Wff2_t(256x1024) bcat(320 f32)
__global__ __launch_bounds__(256) void prep_weights(
    const float* __restrict__ Wv, const float* __restrict__ Woff,
    const float* __restrict__ Wattn, const float* __restrict__ Wout,
    const float* __restrict__ Wff1, const float* __restrict__ Wff2,
    const float* __restrict__ boff, const float* __restrict__ battn,
    ushort* __restrict__ wv_t, ushort* __restrict__ wcat_t,
    ushort* __restrict__ wout_t, ushort* __restrict__ wff1_t,
    ushort* __restrict__ wff2_t, float* __restrict__ bcat)
{
  int i = blockIdx.x * 256 + threadIdx.x;
  if (i < 65536) {                       // Wv_t[n*256+k] = Wv[k*256+n]
    int n = i >> 8, k = i & 255;
    wv_t[i] = f2b(Wv[k * 256 + n]);
    return;
  }
  int j = i - 65536;
  if (j < 81920) {                       // Wcat_t: cols 0..191 off, 192..287 attn, 288..319 zero
    int n = j >> 8, k = j & 255;
    float v = (n < 192) ? Woff[k * 192 + n]
            : (n < 288) ? Wattn[k * 96 + (n - 192)] : 0.f;
    wcat_t[j] = f2b(v);
    return;
  }
  j -= 81920;
  if (j < 65536) {
    int n = j >> 8, k = j & 255;
    wout_t[j] = f2b(Wout[k * 256 + n]);
    return;
  }
  j -= 65536;
  if (j < 262144) {                      // Wff1_t[n*256+k] = Wff1[k*1024+n]
    int n = j >> 8, k = j & 255;
    wff1_t[j] = f2b(Wff1[k * 1024 + n]);
    return;
  }
  j -= 262144;
  if (j < 262144) {                      // Wff2_t[n*1024+k] = Wff2[k*256+n]
    int n = j >> 10, k = j & 1023;
    wff2_t[j] = f2b(Wff2[k * 256 + n]);
    return;
  }
  j -= 262144;
  if (j < 320) bcat[j] = (j < 192) ? boff[j] : (j < 288) ? battn[j - 192] : 0.f;
}

// ---------------- activation prep: bf16 src and q=src+pos, zero pad rows ----
__global__ __launch_bounds__(256) void prep_act(
    const float* __restrict__ src, const float* __restrict__ pos,
    ushort* __restrict__ src_bf, ushort* __restrict__ q_bf)
{
  const size_t e = ((size_t)blockIdx.x * 256 + threadIdx.x) * 4;
  if (e >= (size_t)MP * 256) return;
  ushort4 sb, qb;
  if (e < (size_t)BLTOK * 256) {
    const float4 s = *(const float4*)(src + e);
    const float4 p = *(const float4*)(pos + e);
    sb.x = f2b(s.x); sb.y = f2b(s.y); sb.z = f2b(s.z); sb.w = f2b(s.w);
    qb.x = f2b(s.x + p.x); qb.y = f2b(s.y + p.y);
    qb.z = f2b(s.z + p.z); qb.w = f2b(s.w + p.w);
  } else {
    sb.x = sb.y = sb.z = sb.w = 0;
    qb.x = qb.y = qb.z = qb.w = 0;
  }
  *(ushort4*)(src_bf + e) = sb;
  *(ushort4*)(q_bf + e) = qb;
}

// ---------------- GEMM: C(bf16)[M x N] = A(bf16)[M x K] @ Bt(bf16)[N x K]^T + bias
// EPI: 0 = bias only; 1 = + addf(f32); 2 = relu; 3 = + addb(bf16)
template <int EPI>
__global__ __launch_bounds__(256) void gemm64(
    const ushort* __restrict__ A, const ushort* __restrict__ Bt,
    const float* __restrict__ bias, const float* __restrict__ addf,
    const ushort* __restrict__ addb, ushort* __restrict__ C,
    int Mact, int N, int K)
{
  __shared__ __align__(16) ushort As[64 * 40];  // stride 40 bf16 to spread banks
  __shared__ __align__(16) ushort Bs[64 * 40];
  const int tid = threadIdx.x;
  const int m0 = blockIdx.x * 64, n0 = blockIdx.y * 64;
  const int lrow = tid >> 2, lk = (tid & 3) * 8;
  const ushort* Ag = A + (size_t)(m0 + lrow) * K + lk;
  const ushort* Bg = Bt + (size_t)(n0 + lrow) * K + lk;
  const int wave = tid >> 6, lane = tid & 63;
  const int quad = lane >> 4, l16 = lane & 15;
  f32x4 acc[4] = {};
  for (int k0 = 0; k0 < K; k0 += 32) {
    const uint4 av = *(const uint4*)(Ag + k0);
    const uint4 bv = *(const uint4*)(Bg + k0);
    *(uint4*)(&As[lrow * 40 + lk]) = av;
    *(uint4*)(&Bs[lrow * 40 + lk]) = bv;
    __syncthreads();
    // A frag: lane holds A[m = l16][k = quad*8 + j] (wave's 16-row strip)
    const short8 af = *(const short8*)(&As[(wave * 16 + l16) * 40 + quad * 8]);
#pragma unroll
    for (int nt = 0; nt < 4; nt++) {
      const short8 bf = *(const short8*)(&Bs[(nt * 16 + l16) * 40 + quad * 8]);
      acc[nt] = __builtin_amdgcn_mfma_f32_16x16x32_bf16(af, bf, acc[nt], 0, 0, 0);
    }
    __syncthreads();
  }
  // C/D layout: col = lane&15, row = (lane>>4)*4 + reg   [m89/m91]
#pragma unroll
  for (int nt = 0; nt < 4; nt++) {
    const int col = n0 + nt * 16 + l16;
    const float bb = bias[col];
#pragma unroll
    for (int i = 0; i < 4; i++) {
      const int row = m0 + wave * 16 + quad * 4 + i;
      if (row < Mact) {
        const size_t idx = (size_t)row * N + col;
        float v = acc[nt][i] + bb;
        if (EPI == 1) v += addf[idx];
        if (EPI == 2) v = fmaxf(v, 0.f);
        if (EPI == 3) v += b2f(addb[idx]);
        C[idx] = f2b(v);
      }
    }
  }
}

// ---------------- softmax over 12 attn logits per (token, head), in place ---
__global__ __launch_bounds__(256) void softmax12(ushort* __restrict__ offattn)
{
  const int t = blockIdx.x * 256 + threadIdx.x;
  if (t >= BLTOK * 8) return;
  const int r = t >> 3, h = t & 7;
  ushort* p = offattn + (size_t)r * 320 + 192 + h * 12;
  float v[12], mx = -1e30f;
#pragma unroll
  for (int i = 0; i < 12; i++) { v[i] = b2f(p[i]); mx = fmaxf(mx, v[i]); }
  float s = 0.f;
#pragma unroll
  for (int i = 0; i < 12; i++) { v[i] = expf(v[i] - mx); s += v[i]; }
  const float inv = 1.f / s;
#pragma unroll
  for (int i = 0; i < 12; i++) p[i] = f2b(v[i] * inv);
}

// ---------------- MS-deform-attn bilinear sampling core ---------------------
// block = one token (256 threads: h = tid>>5, c = tid&31)
__global__ __launch_bounds__(256) void deform_sample(
    const ushort* __restrict__ value, const ushort* __restrict__ oa_all,
    const float* __restrict__ refp, ushort* __restrict__ outb)
{
  const int r = blockIdx.x;
  const int b = r / LSP;
  const int tid = threadIdx.x;
  const int h = tid >> 5, c = tid & 31;
  const ushort* oa = oa_all + (size_t)r * 320;
  const float* rp = refp + (size_t)r * 6;
  const int Wl[3] = {100, 50, 25};
  const int Stl[3] = {0, 10000, 12500};
  float acc = 0.f;
#pragma unroll
  for (int lid = 0; lid < 3; lid++) {
    const int W = Wl[lid], st = Stl[lid];   // square levels: H == W
    const float Wf = (float)W;
    const float rx = rp[lid * 2], ry = rp[lid * 2 + 1];
#pragma unroll
    for (int p = 0; p < 4; p++) {
      const float ox = b2f(oa[h * 24 + lid * 8 + p * 2]);
      const float oy = b2f(oa[h * 24 + lid * 8 + p * 2 + 1]);
      const float aw = b2f(oa[192 + h * 12 + lid * 4 + p]);
      // x = loc_x*W - 0.5 (align_corners=False), loc = ref + off/W
      const float x = (rx + ox / Wf) * Wf - 0.5f;
      const float y = (ry + oy / Wf) * Wf - 0.5f;
      const float x0f = floorf(x), y0f = floorf(y);
      const float wx1 = x - x0f, wy1 = y - y0f;
      const float wx0 = 1.f - wx1, wy0 = 1.f - wy1;
      const int ix0 = (int)x0f, iy0 = (int)y0f;
      const bool x0v = (ix0 >= 0) && (ix0 < W);
      const bool x1v = (ix0 + 1 >= 0) && (ix0 + 1 < W);
      const bool y0v = (iy0 >= 0) && (iy0 < W);
      const bool y1v = (iy0 + 1 >= 0) && (iy0 + 1 < W);
      const size_t vbase = ((size_t)b * LSP + st) * 256 + h * 32 + c;
      float v00 = 0.f, v10 = 0.f, v01 = 0.f, v11 = 0.f;
      if (y0v) {
        const size_t rowo = vbase + (size_t)(iy0 * W) * 256;
        if (x0v) v00 = b2f(value[rowo + (size_t)ix0 * 256]);
        if (x1v) v10 = b2f(value[rowo + (size_t)(ix0 + 1) * 256]);
      }
      if (y1v) {
        const size_t rowo = vbase + (size_t)((iy0 + 1) * W) * 256;
        if (x0v) v01 = b2f(value[rowo + (size_t)ix0 * 256]);
        if (x1v) v11 = b2f(value[rowo + (size_t)(ix0 + 1) * 256]);
      }
      acc += aw * (wx0 * wy0 * v00 + wx1 * wy0 * v10 +
                   wx0 * wy1 * v01 + wx1 * wy1 * v11);
    }
  }
  outb[(size_t)r * 256 + tid] = f2b(acc);
}

// ---------------- LayerNorm over 256 (wave per row, 4 rows/block) -----------
template <int OUTF>
__global__ __launch_bounds__(256) void ln256(
    const ushort* __restrict__ in, const float* __restrict__ gg,
    const float* __restrict__ bb, ushort* __restrict__ outb,
    float* __restrict__ outf, int rows)
{
  const int wave = threadIdx.x >> 6, lane = threadIdx.x & 63;
  const int r = blockIdx.x * 4 + wave;
  if (r >= rows) return;
  const ushort* rowp = in + (size_t)r * 256;
  const ushort4 u = *(const ushort4*)(rowp + lane * 4);
  float v[4] = {b2f(u.x), b2f(u.y), b2f(u.z), b2f(u.w)};
  float s = v[0] + v[1] + v[2] + v[3];
  float s2 = v[0] * v[0] + v[1] * v[1] + v[2] * v[2] + v[3] * v[3];
#pragma unroll
  for (int o = 32; o > 0; o >>= 1) {
    s += __shfl_xor(s, o);
    s2 += __shfl_xor(s2, o);
  }
  const float mean = s * (1.f / 256.f);
  const float var = s2 * (1.f / 256.f) - mean * mean;
  const float rstd = rsqrtf(var + 1e-5f);
#pragma unroll
  for (int j = 0; j < 4; j++) {
    const int col = lane * 4 + j;
    const float o = (v[j] - mean) * rstd * gg[col] + bb[col];
    if (OUTF) outf[(size_t)r * 256 + col] = o;
    else outb[(size_t)r * 256 + col] = f2b(o);
  }
}

// ---------------------------------------------------------------------------
extern "C" void kernel_launch(void* const* d_in, const int* in_sizes, int n_in,
                              void* d_out, int out_size, void* d_ws, size_t ws_size,
                              hipStream_t stream)
{
  const float* src   = (const float*)d_in[0];
  const float* pos   = (const float*)d_in[1];
  const float* refp  = (const float*)d_in[2];
  const float* Wv    = (const float*)d_in[3];
  const float* bv    = (const float*)d_in[4];
  const float* Woff  = (const float*)d_in[5];
  const float* boff  = (const float*)d_in[6];
  const float* Wattn = (const float*)d_in[7];
  const float* battn = (const float*)d_in[8];
  const float* Wout  = (const float*)d_in[9];
  const float* bout  = (const float*)d_in[10];
  const float* g1    = (const float*)d_in[11];
  const float* b1    = (const float*)d_in[12];
  const float* Wff1  = (const float*)d_in[13];
  const float* bff1  = (const float*)d_in[14];
  const float* Wff2  = (const float*)d_in[15];
  const float* bff2  = (const float*)d_in[16];
  const float* g2    = (const float*)d_in[17];
  const float* b2    = (const float*)d_in[18];
  float* out = (float*)d_out;
  char* ws = (char*)d_ws;

  // workspace layout (bytes, all 256-aligned)
  ushort* wv_t   = (ushort*)(ws + 0);          //  131072
  ushort* wcat_t = (ushort*)(ws + 131072);     //  163840
  ushort* wout_t = (ushort*)(ws + 294912);     //  131072
  ushort* wff1_t = (ushort*)(ws + 425984);     //  524288
  ushort* wff2_t = (ushort*)(ws + 950272);     //  524288
  float*  bcat   = (float*)(ws + 1474560);     //    1280
  ushort* A1 = (ushort*)(ws + 1475840);        // src_bf  -> attn_out_bf (MP x 256)
  ushort* A2 = (ushort*)(ws + 28378368);       // q_bf    -> x_bf        (MP x 256)
  ushort* A3 = (ushort*)(ws + 55280896);       // value   -> y_bf        (BL x 256)
  ushort* A4 = (ushort*)(ws + 82160896);       // offattn -> xpre        (BL x 320)
  ushort* A5 = (ushort*)(ws + 115760896);      // h                      (MP x 1024)
  // total: 223,371,008 bytes

  // 1) weight prep: 737,600 work items
  prep_weights<<<2882, 256, 0, stream>>>(Wv, Woff, Wattn, Wout, Wff1, Wff2,
                                         boff, battn,
                                         wv_t, wcat_t, wout_t, wff1_t, wff2_t, bcat);
  // 2) activations
  prep_act<<<MP / 4, 256, 0, stream>>>(src, pos, A1, A2);
  // 3) value = src @ Wv + bv
  gemm64<0><<<dim3(MP / 64, 4), 256, 0, stream>>>(A1, wv_t, bv, nullptr, nullptr,
                                                  A3, BLTOK, 256, 256);
  // 4) offattn = q @ Wcat + bcat  (N=320)
  gemm64<0><<<dim3(MP / 64, 5), 256, 0, stream>>>(A2, wcat_t, bcat, nullptr, nullptr,
                                                  A4, BLTOK, 320, 256);
  // 5) softmax over 12 per (token, head)
  softmax12<<<(BLTOK * 8 + 255) / 256, 256, 0, stream>>>(A4);
  // 6) deformable sampling -> attn_out (reuses A1)
  deform_sample<<<BLTOK, 256, 0, stream>>>(A3, A4, refp, A1);
  // 7) xpre = src + attn_out @ Wout + bout (reuses A4)
  gemm64<1><<<dim3(MP / 64, 4), 256, 0, stream>>>(A1, wout_t, bout, src, nullptr,
                                                  A4, BLTOK, 256, 256);
  // 8) LN1 -> x_bf (reuses A2)
  ln256<0><<<BLTOK / 4, 256, 0, stream>>>(A4, g1, b1, A2, nullptr, BLTOK);
  // 9) h = relu(x @ Wff1 + bff1)
  gemm64<2><<<dim3(MP / 64, 16), 256, 0, stream>>>(A2, wff1_t, bff1, nullptr, nullptr,
                                                   A5, BLTOK, 1024, 256);
  // 10) y = x + h @ Wff2 + bff2 (reuses A3)
  gemm64<3><<<dim3(MP / 64, 4), 256, 0, stream>>>(A5, wff2_t, bff2, nullptr, A2,
                                                  A3, BLTOK, 256, 1024);
  // 11) LN2 -> out (f32)
  ln256<1><<<BLTOK / 4, 256, 0, stream>>>(A3, g2, b2, nullptr, out, BLTOK);
}

// Round 2
// 612.433 us; speedup vs baseline: 2.0168x; 2.0168x over previous
//
#include <hip/hip_runtime.h>

// ---------------------------------------------------------------------------
// DeformableTransformer encoder layer, MI355X (gfx950).
// R1 change: deform_sample vectorized — 8 channels/lane (dwordx4 corner
// loads), 32 lanes/token, unconditional clamped loads with zeroed weights.
// ---------------------------------------------------------------------------

#define BLTOK 52500   // B*L tokens
#define MP    52544   // BLTOK padded to multiple of 64
#define LSP   13125   // L (spatial length per batch)

using short8 = __attribute__((ext_vector_type(8))) short;
using f32x4  = __attribute__((ext_vector_type(4))) float;

__device__ __forceinline__ ushort f2b(float f) {
  union { float f; unsigned u; } x; x.f = f;
  unsigned r = (x.u + 0x7fffu + ((x.u >> 16) & 1u)) >> 16;
  return (ushort)r;
}
__device__ __forceinline__ float b2f(ushort h) {
  union { unsigned u; float f; } x; x.u = ((unsigned)h) << 16;
  return x.f;
}

// ---------------- weight prep: transpose to N x K, convert bf16 -------------
__global__ __launch_bounds__(256) void prep_weights(
    const float* __restrict__ Wv, const float* __restrict__ Woff,
    const float* __restrict__ Wattn, const float* __restrict__ Wout,
    const float* __restrict__ Wff1, const float* __restrict__ Wff2,
    const float* __restrict__ boff, const float* __restrict__ battn,
    ushort* __restrict__ wv_t, ushort* __restrict__ wcat_t,
    ushort* __restrict__ wout_t, ushort* __restrict__ wff1_t,
    ushort* __restrict__ wff2_t, float* __restrict__ bcat)
{
  int i = blockIdx.x * 256 + threadIdx.x;
  if (i < 65536) {                       // Wv_t[n*256+k] = Wv[k*256+n]
    int n = i >> 8, k = i & 255;
    wv_t[i] = f2b(Wv[k * 256 + n]);
    return;
  }
  int j = i - 65536;
  if (j < 81920) {                       // Wcat_t: cols 0..191 off, 192..287 attn, 288..319 zero
    int n = j >> 8, k = j & 255;
    float v = (n < 192) ? Woff[k * 192 + n]
            : (n < 288) ? Wattn[k * 96 + (n - 192)] : 0.f;
    wcat_t[j] = f2b(v);
    return;
  }
  j -= 81920;
  if (j < 65536) {
    int n = j >> 8, k = j & 255;
    wout_t[j] = f2b(Wout[k * 256 + n]);
    return;
  }
  j -= 65536;
  if (j < 262144) {                      // Wff1_t[n*256+k] = Wff1[k*1024+n]
    int n = j >> 8, k = j & 255;
    wff1_t[j] = f2b(Wff1[k * 1024 + n]);
    return;
  }
  j -= 262144;
  if (j < 262144) {                      // Wff2_t[n*1024+k] = Wff2[k*256+n]
    int n = j >> 10, k = j & 1023;
    wff2_t[j] = f2b(Wff2[k * 256 + n]);
    return;
  }
  j -= 262144;
  if (j < 320) bcat[j] = (j < 192) ? boff[j] : (j < 288) ? battn[j - 192] : 0.f;
}

// ---------------- activation prep: bf16 src and q=src+pos, zero pad rows ----
__global__ __launch_bounds__(256) void prep_act(
    const float* __restrict__ src, const float* __restrict__ pos,
    ushort* __restrict__ src_bf, ushort* __restrict__ q_bf)
{
  const size_t e = ((size_t)blockIdx.x * 256 + threadIdx.x) * 4;
  if (e >= (size_t)MP * 256) return;
  ushort4 sb, qb;
  if (e < (size_t)BLTOK * 256) {
    const float4 s = *(const float4*)(src + e);
    const float4 p = *(const float4*)(pos + e);
    sb.x = f2b(s.x); sb.y = f2b(s.y); sb.z = f2b(s.z); sb.w = f2b(s.w);
    qb.x = f2b(s.x + p.x); qb.y = f2b(s.y + p.y);
    qb.z = f2b(s.z + p.z); qb.w = f2b(s.w + p.w);
  } else {
    sb.x = sb.y = sb.z = sb.w = 0;
    qb.x = qb.y = qb.z = qb.w = 0;
  }
  *(ushort4*)(src_bf + e) = sb;
  *(ushort4*)(q_bf + e) = qb;
}

// ---------------- GEMM: C(bf16)[M x N] = A(bf16)[M x K] @ Bt(bf16)[N x K]^T + bias
// EPI: 0 = bias only; 1 = + addf(f32); 2 = relu; 3 = + addb(bf16)
template <int EPI>
__global__ __launch_bounds__(256) void gemm64(
    const ushort* __restrict__ A, const ushort* __restrict__ Bt,
    const float* __restrict__ bias, const float* __restrict__ addf,
    const ushort* __restrict__ addb, ushort* __restrict__ C,
    int Mact, int N, int K)
{
  __shared__ __align__(16) ushort As[64 * 40];
  __shared__ __align__(16) ushort Bs[64 * 40];
  const int tid = threadIdx.x;
  const int m0 = blockIdx.x * 64, n0 = blockIdx.y * 64;
  const int lrow = tid >> 2, lk = (tid & 3) * 8;
  const ushort* Ag = A + (size_t)(m0 + lrow) * K + lk;
  const ushort* Bg = Bt + (size_t)(n0 + lrow) * K + lk;
  const int wave = tid >> 6, lane = tid & 63;
  const int quad = lane >> 4, l16 = lane & 15;
  f32x4 acc[4] = {};
  for (int k0 = 0; k0 < K; k0 += 32) {
    const uint4 av = *(const uint4*)(Ag + k0);
    const uint4 bv = *(const uint4*)(Bg + k0);
    *(uint4*)(&As[lrow * 40 + lk]) = av;
    *(uint4*)(&Bs[lrow * 40 + lk]) = bv;
    __syncthreads();
    const short8 af = *(const short8*)(&As[(wave * 16 + l16) * 40 + quad * 8]);
#pragma unroll
    for (int nt = 0; nt < 4; nt++) {
      const short8 bf = *(const short8*)(&Bs[(nt * 16 + l16) * 40 + quad * 8]);
      acc[nt] = __builtin_amdgcn_mfma_f32_16x16x32_bf16(af, bf, acc[nt], 0, 0, 0);
    }
    __syncthreads();
  }
#pragma unroll
  for (int nt = 0; nt < 4; nt++) {
    const int col = n0 + nt * 16 + l16;
    const float bb = bias[col];
#pragma unroll
    for (int i = 0; i < 4; i++) {
      const int row = m0 + wave * 16 + quad * 4 + i;
      if (row < Mact) {
        const size_t idx = (size_t)row * N + col;
        float v = acc[nt][i] + bb;
        if (EPI == 1) v += addf[idx];
        if (EPI == 2) v = fmaxf(v, 0.f);
        if (EPI == 3) v += b2f(addb[idx]);
        C[idx] = f2b(v);
      }
    }
  }
}

// ---------------- softmax over 12 attn logits per (token, head), in place ---
__global__ __launch_bounds__(256) void softmax12(ushort* __restrict__ offattn)
{
  const int t = blockIdx.x * 256 + threadIdx.x;
  if (t >= BLTOK * 8) return;
  const int r = t >> 3, h = t & 7;
  ushort* p = offattn + (size_t)r * 320 + 192 + h * 12;
  float v[12], mx = -1e30f;
#pragma unroll
  for (int i = 0; i < 12; i++) { v[i] = b2f(p[i]); mx = fmaxf(mx, v[i]); }
  float s = 0.f;
#pragma unroll
  for (int i = 0; i < 12; i++) { v[i] = expf(v[i] - mx); s += v[i]; }
  const float inv = 1.f / s;
#pragma unroll
  for (int i = 0; i < 12; i++) p[i] = f2b(v[i] * inv);
}

// ---------------- MS-deform-attn bilinear sampling core (vectorized) --------
// 32 lanes per token: lane l -> head h=l>>2, channel group cg=l&3 (8 ch).
// Block 256 = 8 tokens. Corner loads are unconditional dwordx4 with clamped
// indices; OOB handled by zeroing the bilinear weight.
__global__ __launch_bounds__(256) void deform_sample(
    const ushort* __restrict__ value, const ushort* __restrict__ oa_all,
    const float* __restrict__ refp, ushort* __restrict__ outb)
{
  const int tid = threadIdx.x;
  const int tok = blockIdx.x * 8 + (tid >> 5);
  if (tok >= BLTOK) return;
  const int b = tok / LSP;
  const int l = tid & 31;
  const int h = l >> 2;
  const ushort* oa = oa_all + (size_t)tok * 320;
  const float* rp = refp + (size_t)tok * 6;
  const int Wl[3] = {100, 50, 25};
  const int Stl[3] = {0, 10000, 12500};
  // lane's channel base within a value row: ch = l*8 (== h*32 + cg*8)
  const ushort* vbase = value + (size_t)b * LSP * 256 + l * 8;
  float acc[8] = {};
#pragma unroll
  for (int lid = 0; lid < 3; lid++) {
    const int W = Wl[lid], st = Stl[lid];   // square levels: H == W
    const float Wf = (float)W;
    const float rx = rp[lid * 2], ry = rp[lid * 2 + 1];
#pragma unroll
    for (int p = 0; p < 4; p++) {
      const float ox = b2f(oa[h * 24 + lid * 8 + p * 2]);
      const float oy = b2f(oa[h * 24 + lid * 8 + p * 2 + 1]);
      const float aw = b2f(oa[192 + h * 12 + lid * 4 + p]);
      const float x = (rx + ox / Wf) * Wf - 0.5f;
      const float y = (ry + oy / Wf) * Wf - 0.5f;
      const float x0f = floorf(x), y0f = floorf(y);
      const float wx1 = x - x0f, wy1 = y - y0f;
      const float wx0 = 1.f - wx1, wy0 = 1.f - wy1;
      const int ix0 = (int)x0f, iy0 = (int)y0f;
      const bool x0v = (ix0 >= 0) & (ix0 < W);
      const bool x1v = (ix0 + 1 >= 0) & (ix0 + 1 < W);
      const bool y0v = (iy0 >= 0) & (iy0 < W);
      const bool y1v = (iy0 + 1 >= 0) & (iy0 + 1 < W);
      const float ay0 = aw * wy0, ay1 = aw * wy1;
      float w00 = (x0v & y0v) ? ay0 * wx0 : 0.f;
      float w10 = (x1v & y0v) ? ay0 * wx1 : 0.f;
      float w01 = (x0v & y1v) ? ay1 * wx0 : 0.f;
      float w11 = (x1v & y1v) ? ay1 * wx1 : 0.f;
      const int ix0c = min(max(ix0, 0), W - 1);
      const int ix1c = min(max(ix0 + 1, 0), W - 1);
      const int iy0c = min(max(iy0, 0), W - 1);
      const int iy1c = min(max(iy0 + 1, 0), W - 1);
      const int r00 = st + iy0c * W + ix0c;
      const int r10 = st + iy0c * W + ix1c;
      const int r01 = st + iy1c * W + ix0c;
      const int r11 = st + iy1c * W + ix1c;
      // 4 independent 16B loads (latency overlapped), then 32 FMAs
      const uint4 q00 = *(const uint4*)(vbase + (size_t)r00 * 256);
      const uint4 q10 = *(const uint4*)(vbase + (size_t)r10 * 256);
      const uint4 q01 = *(const uint4*)(vbase + (size_t)r01 * 256);
      const uint4 q11 = *(const uint4*)(vbase + (size_t)r11 * 256);
      const ushort* s00 = (const ushort*)&q00;
      const ushort* s10 = (const ushort*)&q10;
      const ushort* s01 = (const ushort*)&q01;
      const ushort* s11 = (const ushort*)&q11;
#pragma unroll
      for (int j = 0; j < 8; j++) {
        acc[j] += w00 * b2f(s00[j]) + w10 * b2f(s10[j]) +
                  w01 * b2f(s01[j]) + w11 * b2f(s11[j]);
      }
    }
  }
  ushort4 o0, o1;
  o0.x = f2b(acc[0]); o0.y = f2b(acc[1]); o0.z = f2b(acc[2]); o0.w = f2b(acc[3]);
  o1.x = f2b(acc[4]); o1.y = f2b(acc[5]); o1.z = f2b(acc[6]); o1.w = f2b(acc[7]);
  ushort* op = outb + (size_t)tok * 256 + l * 8;
  *(ushort4*)op = o0;
  *(ushort4*)(op + 4) = o1;
}

// ---------------- LayerNorm over 256 (wave per row, 4 rows/block) -----------
template <int OUTF>
__global__ __launch_bounds__(256) void ln256(
    const ushort* __restrict__ in, const float* __restrict__ gg,
    const float* __restrict__ bb, ushort* __restrict__ outb,
    float* __restrict__ outf, int rows)
{
  const int wave = threadIdx.x >> 6, lane = threadIdx.x & 63;
  const int r = blockIdx.x * 4 + wave;
  if (r >= rows) return;
  const ushort* rowp = in + (size_t)r * 256;
  const ushort4 u = *(const ushort4*)(rowp + lane * 4);
  float v[4] = {b2f(u.x), b2f(u.y), b2f(u.z), b2f(u.w)};
  float s = v[0] + v[1] + v[2] + v[3];
  float s2 = v[0] * v[0] + v[1] * v[1] + v[2] * v[2] + v[3] * v[3];
#pragma unroll
  for (int o = 32; o > 0; o >>= 1) {
    s += __shfl_xor(s, o);
    s2 += __shfl_xor(s2, o);
  }
  const float mean = s * (1.f / 256.f);
  const float var = s2 * (1.f / 256.f) - mean * mean;
  const float rstd = rsqrtf(var + 1e-5f);
#pragma unroll
  for (int j = 0; j < 4; j++) {
    const int col = lane * 4 + j;
    const float o = (v[j] - mean) * rstd * gg[col] + bb[col];
    if (OUTF) outf[(size_t)r * 256 + col] = o;
    else outb[(size_t)r * 256 + col] = f2b(o);
  }
}

// ---------------------------------------------------------------------------
extern "C" void kernel_launch(void* const* d_in, const int* in_sizes, int n_in,
                              void* d_out, int out_size, void* d_ws, size_t ws_size,
                              hipStream_t stream)
{
  const float* src   = (const float*)d_in[0];
  const float* pos   = (const float*)d_in[1];
  const float* refp  = (const float*)d_in[2];
  const float* Wv    = (const float*)d_in[3];
  const float* bv    = (const float*)d_in[4];
  const float* Woff  = (const float*)d_in[5];
  const float* boff  = (const float*)d_in[6];
  const float* Wattn = (const float*)d_in[7];
  const float* battn = (const float*)d_in[8];
  const float* Wout  = (const float*)d_in[9];
  const float* bout  = (const float*)d_in[10];
  const float* g1    = (const float*)d_in[11];
  const float* b1    = (const float*)d_in[12];
  const float* Wff1  = (const float*)d_in[13];
  const float* bff1  = (const float*)d_in[14];
  const float* Wff2  = (const float*)d_in[15];
  const float* bff2  = (const float*)d_in[16];
  const float* g2    = (const float*)d_in[17];
  const float* b2    = (const float*)d_in[18];
  float* out = (float*)d_out;
  char* ws = (char*)d_ws;

  ushort* wv_t   = (ushort*)(ws + 0);          //  131072
  ushort* wcat_t = (ushort*)(ws + 131072);     //  163840
  ushort* wout_t = (ushort*)(ws + 294912);     //  131072
  ushort* wff1_t = (ushort*)(ws + 425984);     //  524288
  ushort* wff2_t = (ushort*)(ws + 950272);     //  524288
  float*  bcat   = (float*)(ws + 1474560);     //    1280
  ushort* A1 = (ushort*)(ws + 1475840);        // src_bf  -> attn_out_bf (MP x 256)
  ushort* A2 = (ushort*)(ws + 28378368);       // q_bf    -> x_bf        (MP x 256)
  ushort* A3 = (ushort*)(ws + 55280896);       // value   -> y_bf        (BL x 256)
  ushort* A4 = (ushort*)(ws + 82160896);       // offattn -> xpre        (BL x 320)
  ushort* A5 = (ushort*)(ws + 115760896);      // h                      (MP x 1024)

  prep_weights<<<2882, 256, 0, stream>>>(Wv, Woff, Wattn, Wout, Wff1, Wff2,
                                         boff, battn,
                                         wv_t, wcat_t, wout_t, wff1_t, wff2_t, bcat);
  prep_act<<<MP / 4, 256, 0, stream>>>(src, pos, A1, A2);
  gemm64<0><<<dim3(MP / 64, 4), 256, 0, stream>>>(A1, wv_t, bv, nullptr, nullptr,
                                                  A3, BLTOK, 256, 256);
  gemm64<0><<<dim3(MP / 64, 5), 256, 0, stream>>>(A2, wcat_t, bcat, nullptr, nullptr,
                                                  A4, BLTOK, 320, 256);
  softmax12<<<(BLTOK * 8 + 255) / 256, 256, 0, stream>>>(A4);
  deform_sample<<<(BLTOK + 7) / 8, 256, 0, stream>>>(A3, A4, refp, A1);
  gemm64<1><<<dim3(MP / 64, 4), 256, 0, stream>>>(A1, wout_t, bout, src, nullptr,
                                                  A4, BLTOK, 256, 256);
  ln256<0><<<BLTOK / 4, 256, 0, stream>>>(A4, g1, b1, A2, nullptr, BLTOK);
  gemm64<2><<<dim3(MP / 64, 16), 256, 0, stream>>>(A2, wff1_t, bff1, nullptr, nullptr,
                                                   A5, BLTOK, 1024, 256);
  gemm64<3><<<dim3(MP / 64, 4), 256, 0, stream>>>(A5, wff2_t, bff2, nullptr, A2,
                                                  A3, BLTOK, 256, 1024);
  ln256<1><<<BLTOK / 4, 256, 0, stream>>>(A3, g2, b2, nullptr, out, BLTOK);
}